// Round 6
// baseline (144.421 us; speedup 1.0000x reference)
//
#include <hip/hip_runtime.h>
#include <hip/hip_bf16.h>

// BlurredNoise via MFMA implicit GEMM, round 14 = R13 + MT=2 (64t/wave).
// R13 clean measurement: B-refill VMEM is the wall (8 waves/CU x ~540
// dwordx4 x ~17cy = 73k of 151k cyc/CU); LDS fixed (A -80%); MFMA 21%.
// Fix: each wave computes TWO 32-row m-tiles sharing every B fragment ->
// per-CU B-VMEM instrs halve. Grid 1024 (1 wave/SIMD), so also cut the
// exposed A ds_read latency: prefetch distance 2 via 4-slot static ring
// (all indices compile-time, rule #20). Staged 520-float window already
// covers 64t (max entry 510 < 520 at U<=28) -> segments re-cut U<=28:
// W4 U21 (one wasted all-zero step at s=20), W3 U28. All R13-verified
// layouts unchanged.
// out[bc][F][t] = scale[F] * sum_j x[bc][t+j] * k[F][j]

#define KS      5000
#define IN_SEQ  9095
#define T_OUT   4096
#define NBC     16
#define NF      128
#define NSTEP   313               // 16-tap k-steps
#define SWZSTEP 328               // padded per-tile step stride (rows)
#define CSTRIDE 1056              // bytes; /4 = 264 == 8 mod 32 -> uniform banks
#define XBUF    (8*CSTRIDE)       // 8448 B: 8 shifted copies, single buffer
#define XPS     9344              // padded x row stride (floats), front pad 32
#define XTAIL   256               // zero tail for staging over-reads (unread)
#define SWZ_BYTES (4*SWZSTEP*1024)    // 1,343,488

typedef __attribute__((ext_vector_type(8)))  short v8s;
typedef __attribute__((ext_vector_type(4)))  float v4f;
typedef __attribute__((ext_vector_type(16))) float v16f;

__device__ __forceinline__ unsigned short f2b(float v) {
  union { __hip_bfloat16 h; unsigned short u; } cv;
  cv.h = __float2bfloat16(v);   // RNE
  return cv.u;
}

// ---- fused pre-kernel: (a) filters -> 32x32x16 B-frags; (b) padded x copy ----
__global__ void build_pre(const float* __restrict__ filt,
                          const float* __restrict__ noise,
                          unsigned short* __restrict__ swz,
                          float* __restrict__ xpad) {
  const int b = blockIdx.x;
  if (b < 313) {                       // swz job: 4 tiles x 313 steps, 64 lanes/frag
    const int i = b * 256 + threadIdx.x;
    if (i >= 4 * NSTEP * 64) return;
    const int lane = i & 63;
    const int frag = i >> 6;
    const int ft = frag / NSTEP;
    const int s  = frag - ft * NSTEP;
    const int col = lane & 31;          // filter within tile
    const int hi  = lane >> 5;          // k-group (8 taps)
    const int jg0 = KS - 16 * (s + 1) + 8 * hi;
    const float* row = filt + (size_t)(ft * 32 + col) * KS;
    unsigned short o[8];
    #pragma unroll
    for (int j = 0; j < 8; ++j) {
      int jg = jg0 + j;
      int jc = jg < 0 ? 0 : jg;          // clamp ADDRESS, select VALUE
      float v = (jg >= 0) ? row[jc] : 0.0f;
      o[j] = f2b(v);
    }
    *(uint4*)(swz + (((size_t)(ft * SWZSTEP + s)) << 9) + (lane << 3)) = *(uint4*)o;
  } else {                             // xpad job: 16 x XPS (+tail), zeros outside
    const int i = (b - 313) * 256 + threadIdx.x;
    if (i >= NBC * XPS + XTAIL) return;
    const int r = i / XPS;
    const int pcol = i - r * XPS;
    const int lg = pcol - 32;
    xpad[i] = (r < NBC && lg >= 0 && lg < IN_SEQ) ? noise[r * IN_SEQ + lg] : 0.0f;
  }
}

// ---- one single-group constant-width segment of the k-loop ----
// W: live 32-F tiles (tiles 4-W..3); U: steps (<=28, staging window cap at
// MT=2); SB: first step; D: B-prefetch depth. Fully straight-line: stage x
// window once, then U steps of {A ring prefetch (dist 2, 2 m-streams),
// 2W MFMA, W B-refill global b128}. All register indices compile-time.
// xb: LDS base (NO restrict - staging stores and A-reads load through the
// same provenance, ds order preserved).
template<int W, int U, int SB, int D>
__device__ __forceinline__ void run_seg(
    const char* __restrict__ swzg, const float* __restrict__ xn,
    char* xb, int xrd_off, int t0, int lane, v16f (&acc)[2][4])
{
  v8s breg[D][W];
  v8s areg[4][2];                      // [ring slot][m-stream]
  const char* xrd = xb + xrd_off;      // may-alias xb: ds ordering preserved

  const char* sp[W];
  #pragma unroll
  for (int w = 0; w < W; ++w)
    sp[w] = swzg + (((size_t)((4 - W + w) * SWZSTEP + SB)) << 10) + 16 * lane;

  // stage this segment's x window: 8 shifted bf16 copies of 520 entries
  {
    const int wb = t0 + KS - 16 * (SB + U);
    float4 xr[4];
    #pragma unroll
    for (int ii = 0; ii < 4; ++ii)
      xr[ii] = *(const float4*)(xn + (wb + 8 * lane + 4 * ii));
    const float* f = (const float*)xr;
    unsigned u8v[8];
    #pragma unroll
    for (int j = 0; j < 8; ++j)
      u8v[j] = (unsigned)f2b(f[2 * j]) | ((unsigned)f2b(f[2 * j + 1]) << 16);
    auto AL = [](unsigned hi, unsigned lo) { return (lo >> 16) | (hi << 16); };
    char* buf = xb + 16 * lane;
    #pragma unroll
    for (int c = 0; c < 8; ++c) {
      const int h = c >> 1;
      uint4 wv;
      if ((c & 1) == 0)
        wv = (uint4){u8v[h], u8v[h + 1], u8v[h + 2], u8v[h + 3]};
      else
        wv = (uint4){AL(u8v[h + 1], u8v[h]),     AL(u8v[h + 2], u8v[h + 1]),
                     AL(u8v[h + 3], u8v[h + 2]), AL(u8v[h + 4], u8v[h + 3])};
      *(uint4*)(buf + c * CSTRIDE) = wv;
    }
  }

  // B prologue depth D; A ring slots 0,1 = steps 0,1 (offsets walk down)
  #pragma unroll
  for (int d = 0; d < D; ++d)
    #pragma unroll
    for (int w = 0; w < W; ++w)
      breg[d][w] = *(const v8s*)(sp[w] + (d << 10));
  #pragma unroll
  for (int j = 0; j < 2; ++j)
    #pragma unroll
    for (int m = 0; m < 2; ++m)
      areg[j][m] = *(const v8s*)(xrd + 64 * m + 32 * (U - 1 - j));

  #pragma unroll
  for (int i = 0; i < U; ++i) {
    // A prefetch for step i+2 (dead re-read near segment end)
    const int un = (i + 2 < U) ? (U - 3 - i) : 0;
    #pragma unroll
    for (int m = 0; m < 2; ++m)
      areg[(i + 2) & 3][m] = *(const v8s*)(xrd + 64 * m + 32 * un);
    // MFMA: one A fragment per m-stream x W live B tiles (B shared)
    #pragma unroll
    for (int w = 0; w < W; ++w)
      #pragma unroll
      for (int m = 0; m < 2; ++m)
        acc[m][4 - W + w] = __builtin_amdgcn_mfma_f32_32x32x16_bf16(
            areg[i & 3][m], breg[i % D][w], acc[m][4 - W + w], 0, 0, 0);
    // B refill: slot i%D <- step i+D (over-reads land in pad rows, unused)
    #pragma unroll
    for (int w = 0; w < W; ++w)
      breg[i % D][w] = *(const v8s*)(sp[w] + ((i + D) << 10));
  }
}

// ---- main kernel: 1024 blocks x 64 threads, identical waves, barrier-free ----
__global__ __launch_bounds__(64, 1) void blur_mfma(
    const float* __restrict__ xpad,
    const unsigned short* __restrict__ swz,
    const float* __restrict__ scale,
    float* __restrict__ out)
{
  __shared__ __align__(16) char xb[XBUF];   // 8448 B
  const int lane = threadIdx.x;
  const int b  = blockIdx.x;
  const int bc = b >> 6;                 // 16 bc x 64 t-chunks
  const int t0 = (b & 63) << 6;          // 64 output t per wave (2 m-tiles)
  const int row = lane & 31, hi = lane >> 5;
  const float* __restrict__ xn = xpad + (size_t)bc * XPS + 32;  // logical origin
  const char* swzg = (const char*)swz;
  // A-read: copy c=row&7, byte 16*(row>>3) + 16*hi (+32*u' per step, +64 per m)
  const int xrd_off = (row & 7) * CSTRIDE + 16 * (row >> 3) + 16 * hi;

  v16f acc[2][4];
  #pragma unroll
  for (int m = 0; m < 2; ++m)
    #pragma unroll
    for (int n = 0; n < 4; ++n)
      #pragma unroll
      for (int j = 0; j < 16; ++j) acc[m][n][j] = 0.0f;

  // segments <W, U, SB, D>, all single-group, U<=28; live: W4 s<20(+1 pad
  // step, all-zero B), W3 <49, W2 <124, W1 <313. 21+28+3*25+7*27 = 313.
  run_seg<4, 21,   0,  3>(swzg, xn, xb, xrd_off, t0, lane, acc);
  run_seg<3, 28,  21,  4>(swzg, xn, xb, xrd_off, t0, lane, acc);
  run_seg<2, 25,  49,  6>(swzg, xn, xb, xrd_off, t0, lane, acc);
  run_seg<2, 25,  74,  6>(swzg, xn, xb, xrd_off, t0, lane, acc);
  run_seg<2, 25,  99,  6>(swzg, xn, xb, xrd_off, t0, lane, acc);
  run_seg<1, 27, 124, 12>(swzg, xn, xb, xrd_off, t0, lane, acc);
  run_seg<1, 27, 151, 12>(swzg, xn, xb, xrd_off, t0, lane, acc);
  run_seg<1, 27, 178, 12>(swzg, xn, xb, xrd_off, t0, lane, acc);
  run_seg<1, 27, 205, 12>(swzg, xn, xb, xrd_off, t0, lane, acc);
  run_seg<1, 27, 232, 12>(swzg, xn, xb, xrd_off, t0, lane, acc);
  run_seg<1, 27, 259, 12>(swzg, xn, xb, xrd_off, t0, lane, acc);
  run_seg<1, 27, 286, 12>(swzg, xn, xb, xrd_off, t0, lane, acc);

  // epilogue: D col=lane&31 -> F, row=(reg&3)+8*(reg>>2)+4*hi -> t offset
  #pragma unroll
  for (int m = 0; m < 2; ++m)
    #pragma unroll
    for (int n = 0; n < 4; ++n) {
      const int F = 32 * n + row;
      const float sc = scale[F];
      float* op = out + (size_t)(bc * NF + F) * T_OUT + t0 + 32 * m + 4 * hi;
      #pragma unroll
      for (int r2 = 0; r2 < 4; ++r2) {
        v4f o = {acc[m][n][4 * r2] * sc, acc[m][n][4 * r2 + 1] * sc,
                 acc[m][n][4 * r2 + 2] * sc, acc[m][n][4 * r2 + 3] * sc};
        *(v4f*)(op + 8 * r2) = o;
      }
    }
}

extern "C" void kernel_launch(void* const* d_in, const int* in_sizes, int n_in,
                              void* d_out, int out_size, void* d_ws, size_t ws_size,
                              hipStream_t stream) {
  const float* noise = (const float*)d_in[0];   // (2, 8, 9095) fp32
  const float* filt  = (const float*)d_in[1];   // (128, 5000) fp32
  const float* scale = (const float*)d_in[2];   // (1, 128, 1) fp32
  float* out = (float*)d_out;                   // (2, 1024, 4096) fp32

  unsigned short* swz = (unsigned short*)d_ws;              // 1.34 MB
  float* xpad = (float*)((char*)d_ws + SWZ_BYTES);          // 16 x 9344 fp32 + tail

  const int pad_blocks = (NBC * XPS + XTAIL + 255) / 256;   // 585
  build_pre<<<313 + pad_blocks, 256, 0, stream>>>(filt, noise, swz, xpad);
  blur_mfma<<<1024, 64, 0, stream>>>(xpad, swz, scale, out);
}

// Round 7
// 138.110 us; speedup vs baseline: 1.0457x; 1.0457x over previous
//
#include <hip/hip_runtime.h>
#include <hip/hip_bf16.h>

// BlurredNoise via MFMA implicit GEMM, round 15 = MT=2 + k-split 2-wave blocks.
// R14 lesson: MT=2 at 1 wave/SIMD exposes all per-wave latency (80us, 192k cyc
// vs 109k of pipe demand). MFMA cost recalibrated: 32x32x16 = 32.3 cyc/SIMD
// (m119 8.07 cyc/CU x 4) -> R13's 21% MfmaUtil closes exactly. Need MT=2's
// B-halving AND 2 waves/SIMD: t-space is exhausted, so split k. 1024 blocks
// x 2 waves; both waves own the same 64-t tile; wave0 k-steps 0..91 (254
// tile-steps), wave1 92..312 (253); 2-round 16KB LDS reduction (reuses dead
// x region), wave0 stores. SB is now a RUNTIME arg so repeated segments share
// one code body (I$: two divergent paths ~17KB < 32KB). Register indices all
// compile-time (rule #20).
// out[bc][F][t] = scale[F] * sum_j x[bc][t+j] * k[F][j]

#define KS      5000
#define IN_SEQ  9095
#define T_OUT   4096
#define NBC     16
#define NF      128
#define NSTEP   313               // 16-tap k-steps
#define SWZSTEP 328               // padded per-tile step stride (rows)
#define CSTRIDE 1056              // bytes; /4 = 264 == 8 mod 32 -> uniform banks
#define XBUF    (8*CSTRIDE)       // 8448 B: 8 shifted copies, per-wave buffer
#define XPS     9344              // padded x row stride (floats), front pad 32
#define XTAIL   256               // zero tail for staging over-reads (unread)
#define SWZ_BYTES (4*SWZSTEP*1024)    // 1,343,488

typedef __attribute__((ext_vector_type(8)))  short v8s;
typedef __attribute__((ext_vector_type(4)))  float v4f;
typedef __attribute__((ext_vector_type(16))) float v16f;

__device__ __forceinline__ unsigned short f2b(float v) {
  union { __hip_bfloat16 h; unsigned short u; } cv;
  cv.h = __float2bfloat16(v);   // RNE
  return cv.u;
}

// ---- fused pre-kernel: (a) filters -> 32x32x16 B-frags; (b) padded x copy ----
__global__ void build_pre(const float* __restrict__ filt,
                          const float* __restrict__ noise,
                          unsigned short* __restrict__ swz,
                          float* __restrict__ xpad) {
  const int b = blockIdx.x;
  if (b < 313) {                       // swz job: 4 tiles x 313 steps, 64 lanes/frag
    const int i = b * 256 + threadIdx.x;
    if (i >= 4 * NSTEP * 64) return;
    const int lane = i & 63;
    const int frag = i >> 6;
    const int ft = frag / NSTEP;
    const int s  = frag - ft * NSTEP;
    const int col = lane & 31;          // filter within tile
    const int hi  = lane >> 5;          // k-group (8 taps)
    const int jg0 = KS - 16 * (s + 1) + 8 * hi;
    const float* row = filt + (size_t)(ft * 32 + col) * KS;
    unsigned short o[8];
    #pragma unroll
    for (int j = 0; j < 8; ++j) {
      int jg = jg0 + j;
      int jc = jg < 0 ? 0 : jg;          // clamp ADDRESS, select VALUE
      float v = (jg >= 0) ? row[jc] : 0.0f;
      o[j] = f2b(v);
    }
    *(uint4*)(swz + (((size_t)(ft * SWZSTEP + s)) << 9) + (lane << 3)) = *(uint4*)o;
  } else {                             // xpad job: 16 x XPS (+tail), zeros outside
    const int i = (b - 313) * 256 + threadIdx.x;
    if (i >= NBC * XPS + XTAIL) return;
    const int r = i / XPS;
    const int pcol = i - r * XPS;
    const int lg = pcol - 32;
    xpad[i] = (r < NBC && lg >= 0 && lg < IN_SEQ) ? noise[r * IN_SEQ + lg] : 0.0f;
  }
}

// ---- one single-group constant-width segment of the k-loop ----
// W: live 32-F tiles (tiles 4-W..3); U: steps (<=28, staging window cap at
// MT=2); D: B-prefetch depth; SB: first step (RUNTIME - shared code body for
// repeated segments). Straight-line: stage x window once, then U steps of
// {A ring prefetch (dist 2, 2 m-streams), 2W MFMA, W B-refill global b128}.
// All register indices compile-time. xw: this wave's LDS base (NO restrict -
// staging stores and A-reads load through the same provenance).
template<int W, int U, int D>
__device__ __forceinline__ void run_seg(
    const char* __restrict__ swzg, const float* __restrict__ xn,
    char* xw, int xrd_off, int t0, int lane, int SB, v16f (&acc)[2][4])
{
  v8s breg[D][W];
  v8s areg[4][2];                      // [ring slot][m-stream]
  const char* xrd = xw + xrd_off;      // may-alias xw: ds ordering preserved

  const char* sp[W];
  #pragma unroll
  for (int w = 0; w < W; ++w)
    sp[w] = swzg + (((size_t)((4 - W + w) * SWZSTEP + SB)) << 10) + 16 * lane;

  // stage this segment's x window: 8 shifted bf16 copies of 520 entries
  {
    const int wb = t0 + KS - 16 * (SB + U);
    float4 xr[4];
    #pragma unroll
    for (int ii = 0; ii < 4; ++ii)
      xr[ii] = *(const float4*)(xn + (wb + 8 * lane + 4 * ii));
    const float* f = (const float*)xr;
    unsigned u8v[8];
    #pragma unroll
    for (int j = 0; j < 8; ++j)
      u8v[j] = (unsigned)f2b(f[2 * j]) | ((unsigned)f2b(f[2 * j + 1]) << 16);
    auto AL = [](unsigned hi, unsigned lo) { return (lo >> 16) | (hi << 16); };
    char* buf = xw + 16 * lane;
    #pragma unroll
    for (int c = 0; c < 8; ++c) {
      const int h = c >> 1;
      uint4 wv;
      if ((c & 1) == 0)
        wv = (uint4){u8v[h], u8v[h + 1], u8v[h + 2], u8v[h + 3]};
      else
        wv = (uint4){AL(u8v[h + 1], u8v[h]),     AL(u8v[h + 2], u8v[h + 1]),
                     AL(u8v[h + 3], u8v[h + 2]), AL(u8v[h + 4], u8v[h + 3])};
      *(uint4*)(buf + c * CSTRIDE) = wv;
    }
  }

  // B prologue depth D; A ring slots 0,1 = steps 0,1 (offsets walk down)
  #pragma unroll
  for (int d = 0; d < D; ++d)
    #pragma unroll
    for (int w = 0; w < W; ++w)
      breg[d][w] = *(const v8s*)(sp[w] + (d << 10));
  #pragma unroll
  for (int j = 0; j < 2; ++j)
    #pragma unroll
    for (int m = 0; m < 2; ++m)
      areg[j][m] = *(const v8s*)(xrd + 64 * m + 32 * (U - 1 - j));

  #pragma unroll
  for (int i = 0; i < U; ++i) {
    // A prefetch for step i+2 (dead re-read near segment end)
    const int un = (i + 2 < U) ? (U - 3 - i) : 0;
    #pragma unroll
    for (int m = 0; m < 2; ++m)
      areg[(i + 2) & 3][m] = *(const v8s*)(xrd + 64 * m + 32 * un);
    // MFMA: one A fragment per m-stream x W live B tiles (B shared)
    #pragma unroll
    for (int w = 0; w < W; ++w)
      #pragma unroll
      for (int m = 0; m < 2; ++m)
        acc[m][4 - W + w] = __builtin_amdgcn_mfma_f32_32x32x16_bf16(
            areg[i & 3][m], breg[i % D][w], acc[m][4 - W + w], 0, 0, 0);
    // B refill: slot i%D <- step i+D (over-reads land in pad rows, unused)
    #pragma unroll
    for (int w = 0; w < W; ++w)
      breg[i % D][w] = *(const v8s*)(sp[w] + ((i + D) << 10));
  }
}

// ---- main kernel: 1024 blocks x 128 threads (2 waves k-split one 64t tile) ----
__global__ __launch_bounds__(128, 2) void blur_mfma(
    const float* __restrict__ xpad,
    const unsigned short* __restrict__ swz,
    const float* __restrict__ scale,
    float* __restrict__ out)
{
  __shared__ __align__(16) char xb[2 * XBUF];   // 16,896 B (per-wave x regions)
  const int tid  = threadIdx.x;
  const int lane = tid & 63;
  const int wid  = tid >> 6;
  const int b  = blockIdx.x;
  const int bc = b >> 6;                 // 16 bc x 64 t-chunks
  const int t0 = (b & 63) << 6;          // 64 output t per block (2 m-tiles)
  const int row = lane & 31, hi = lane >> 5;
  const float* __restrict__ xn = xpad + (size_t)bc * XPS + 32;  // logical origin
  const char* swzg = (const char*)swz;
  char* xw = xb + wid * XBUF;            // this wave's staging region
  // A-read: copy c=row&7, byte 16*(row>>3) + 16*hi (+32*u' per step, +64 per m)
  const int xrd_off = (row & 7) * CSTRIDE + 16 * (row >> 3) + 16 * hi;

  v16f acc[2][4];
  #pragma unroll
  for (int m = 0; m < 2; ++m)
    #pragma unroll
    for (int n = 0; n < 4; ++n)
      #pragma unroll
      for (int j = 0; j < 16; ++j) acc[m][n][j] = 0.0f;

  // k-split: wave0 s0..91 (254 tile-steps), wave1 s92..312 (253).
  // live widths: W4 s<20 (+1 zero-B pad step), W3 <49, W2 <124, W1 <313.
  if (wid == 0) {
    run_seg<4, 21, 3>(swzg, xn, xw, xrd_off, t0, lane,  0, acc);
    run_seg<3, 28, 4>(swzg, xn, xw, xrd_off, t0, lane, 21, acc);
    run_seg<2, 25, 6>(swzg, xn, xw, xrd_off, t0, lane, 49, acc);
    run_seg<2, 18, 6>(swzg, xn, xw, xrd_off, t0, lane, 74, acc);
  } else {
    #pragma unroll 1
    for (int r = 0; r < 2; ++r)
      run_seg<2, 16, 6>(swzg, xn, xw, xrd_off, t0, lane, 92 + 16 * r, acc);
    #pragma unroll 1
    for (int r = 0; r < 7; ++r)
      run_seg<1, 27, 12>(swzg, xn, xw, xrd_off, t0, lane, 124 + 27 * r, acc);
  }

  // cross-wave reduction: 2 rounds of 16KB through the (dead) x region.
  // layout ((n*4+r)<<10) + 16*lane: lane-contiguous 16B -> conflict-free.
  __syncthreads();
  #pragma unroll
  for (int mm = 0; mm < 2; ++mm) {
    if (wid == 1) {
      #pragma unroll
      for (int n = 0; n < 4; ++n)
        #pragma unroll
        for (int r2 = 0; r2 < 4; ++r2) {
          v4f v = {acc[mm][n][4 * r2],     acc[mm][n][4 * r2 + 1],
                   acc[mm][n][4 * r2 + 2], acc[mm][n][4 * r2 + 3]};
          *(v4f*)(xb + ((n * 4 + r2) << 10) + 16 * lane) = v;
        }
    }
    __syncthreads();
    if (wid == 0) {
      #pragma unroll
      for (int n = 0; n < 4; ++n)
        #pragma unroll
        for (int r2 = 0; r2 < 4; ++r2) {
          v4f v = *(const v4f*)(xb + ((n * 4 + r2) << 10) + 16 * lane);
          acc[mm][n][4 * r2]     += v[0];
          acc[mm][n][4 * r2 + 1] += v[1];
          acc[mm][n][4 * r2 + 2] += v[2];
          acc[mm][n][4 * r2 + 3] += v[3];
        }
    }
    __syncthreads();                   // WAR guard before next round's writes
  }

  // epilogue (wave0): D col=lane&31 -> F, row=(reg&3)+8*(reg>>2)+4*hi -> t
  if (wid == 0) {
    #pragma unroll
    for (int m = 0; m < 2; ++m)
      #pragma unroll
      for (int n = 0; n < 4; ++n) {
        const int F = 32 * n + row;
        const float sc = scale[F];
        float* op = out + (size_t)(bc * NF + F) * T_OUT + t0 + 32 * m + 4 * hi;
        #pragma unroll
        for (int r2 = 0; r2 < 4; ++r2) {
          v4f o = {acc[m][n][4 * r2] * sc, acc[m][n][4 * r2 + 1] * sc,
                   acc[m][n][4 * r2 + 2] * sc, acc[m][n][4 * r2 + 3] * sc};
          *(v4f*)(op + 8 * r2) = o;
        }
      }
  }
}

extern "C" void kernel_launch(void* const* d_in, const int* in_sizes, int n_in,
                              void* d_out, int out_size, void* d_ws, size_t ws_size,
                              hipStream_t stream) {
  const float* noise = (const float*)d_in[0];   // (2, 8, 9095) fp32
  const float* filt  = (const float*)d_in[1];   // (128, 5000) fp32
  const float* scale = (const float*)d_in[2];   // (1, 128, 1) fp32
  float* out = (float*)d_out;                   // (2, 1024, 4096) fp32

  unsigned short* swz = (unsigned short*)d_ws;              // 1.34 MB
  float* xpad = (float*)((char*)d_ws + SWZ_BYTES);          // 16 x 9344 fp32 + tail

  const int pad_blocks = (NBC * XPS + XTAIL + 255) / 256;   // 585
  build_pre<<<313 + pad_blocks, 256, 0, stream>>>(filt, noise, swz, xpad);
  blur_mfma<<<1024, 128, 0, stream>>>(xpad, swz, scale, out);
}

// Round 8
// 113.150 us; speedup vs baseline: 1.2764x; 1.2206x over previous
//
#include <hip/hip_runtime.h>
#include <hip/hip_bf16.h>

// BlurredNoise via MFMA implicit GEMM, round 16 = ROLLED LOOPS (I-fetch fix).
// R8..R15 post-mortem: elapsed/code-bytes is ~constant (2.9-5.1 cyc/B) across
// five different dataflows; TLP and VMEM halving both no-ops -> the wall is
// INSTRUCTION FETCH of 38-50KB straight-line bodies streaming from L2 (~1-2
// B/cy/CU), not any data pipe. Fix: uniform 24-step rolled window bodies
// (W3:16) with runtime outer loops, one instantiation per W, ~16KB total
// code, hot bodies ~5KB -> I$-resident, fetched once, reused 8x.
// Structure kept from R15 (verified): MT=2 (64t), 2-wave k-split blocks
// (wave0: W4+W3x2+W2x2 = 288 ts; wave1: W2x1+W1x8 = 240 ts), LDS reduction,
// wave0 stores. All register indices compile-time (UB%4==0, UB%D==0).
// x windows double-buffered per wave; window g+1 staged at top of iter g
// (in-order LDS FIFO covers the ii=UB-2/UB-1 cross-window prefetches).
// Bank fix: CSTRIDE 1040 (260 words == 4 mod 32 -> uniform banks both ways).
// out[bc][F][t] = scale[F] * sum_j x[bc][t+j] * k[F][j]

#define KS      5000
#define IN_SEQ  9095
#define T_OUT   4096
#define NBC     16
#define NF      128
#define SWZSTEP 352               // B rows per tile (s>=313 all-zero via clamp)
#define CSTRIDE 1040              // bytes; /4 = 260 == 4 mod 32 -> uniform banks
#define XBUF    (8*CSTRIDE)       // 8320 B: 8 shifted copies, one window buffer
#define FRONT   128               // xpad front zero pad (floats)
#define XPS     9312              // padded x row stride (floats)
#define SWZ_BYTES (4*SWZSTEP*1024)    // 1,441,792

typedef __attribute__((ext_vector_type(8)))  short v8s;
typedef __attribute__((ext_vector_type(4)))  float v4f;
typedef __attribute__((ext_vector_type(16))) float v16f;

__device__ __forceinline__ unsigned short f2b(float v) {
  union { __hip_bfloat16 h; unsigned short u; } cv;
  cv.h = __float2bfloat16(v);   // RNE
  return cv.u;
}

// ---- fused pre-kernel: (a) filters -> 32x32x16 B-frags; (b) padded x copy ----
__global__ void build_pre(const float* __restrict__ filt,
                          const float* __restrict__ noise,
                          unsigned short* __restrict__ swz,
                          float* __restrict__ xpad) {
  const int b = blockIdx.x;
  if (b < 352) {                       // swz job: 4 tiles x 352 rows, 64 lanes/frag
    const int i = b * 256 + threadIdx.x;
    if (i >= 4 * SWZSTEP * 64) return;
    const int lane = i & 63;
    const int frag = i >> 6;
    const int ft = frag / SWZSTEP;
    const int s  = frag - ft * SWZSTEP;
    const int col = lane & 31;          // filter within tile
    const int hi  = lane >> 5;          // k-group (8 taps)
    const int jg0 = KS - 16 * (s + 1) + 8 * hi;
    const float* row = filt + (size_t)(ft * 32 + col) * KS;
    unsigned short o[8];
    #pragma unroll
    for (int j = 0; j < 8; ++j) {
      int jg = jg0 + j;
      int jc = jg < 0 ? 0 : jg;          // clamp ADDRESS, select VALUE
      float v = (jg >= 0 && jg < KS) ? row[jc] : 0.0f;
      o[j] = f2b(v);
    }
    *(uint4*)(swz + (((size_t)(ft * SWZSTEP + s)) << 9) + (lane << 3)) = *(uint4*)o;
  } else {                             // xpad job: 16 x XPS, zeros outside data
    const int i = (b - 352) * 256 + threadIdx.x;
    if (i >= NBC * XPS) return;
    const int r = i / XPS;
    const int pcol = i - r * XPS;
    const int lg = pcol - FRONT;
    xpad[i] = (lg >= 0 && lg < IN_SEQ) ? noise[r * IN_SEQ + lg] : 0.0f;
  }
}

// ---- one rolled region of the k-loop ----
// W: live 32-F tiles (tiles 4-W..3); UB: steps/window (24, W3:16; UB%4==0,
// UB%D==0); D: B-prefetch depth; sb0/iters RUNTIME. Per iter: stage window
// g+1 (double-buffered), UB steps of {A ring prefetch dist 2 (2 m-streams),
// 2W MFMA, W B-refill}. All register indices compile-time.
template<int W, int UB, int D>
__device__ __forceinline__ void run_roll(
    const char* __restrict__ swzg, const float* __restrict__ xn,
    char* xw, int xrd_off, int t0, int lane, int sb0, int iters,
    v16f (&acc)[2][4])
{
  v8s breg[D][W];
  v8s areg[4][2];                      // [ring slot][m-stream]

  const char* sp[W];
  #pragma unroll
  for (int w = 0; w < W; ++w)
    sp[w] = swzg + (((size_t)((4 - W + w) * SWZSTEP + sb0)) << 10) + 16 * lane;

  auto stage = [&](char* buf, int sb) {   // stage window starting at step sb
    const int wb = t0 + KS - 16 * (sb + UB);
    float4 xr[4];
    #pragma unroll
    for (int ii = 0; ii < 4; ++ii)
      xr[ii] = *(const float4*)(xn + (wb + 8 * lane + 4 * ii));
    const float* f = (const float*)xr;
    unsigned u8v[8];
    #pragma unroll
    for (int j = 0; j < 8; ++j)
      u8v[j] = (unsigned)f2b(f[2 * j]) | ((unsigned)f2b(f[2 * j + 1]) << 16);
    auto AL = [](unsigned hi, unsigned lo) { return (lo >> 16) | (hi << 16); };
    char* bufl = buf + 16 * lane;
    #pragma unroll
    for (int c = 0; c < 8; ++c) {
      const int h = c >> 1;
      uint4 wv;
      if ((c & 1) == 0)
        wv = (uint4){u8v[h], u8v[h + 1], u8v[h + 2], u8v[h + 3]};
      else
        wv = (uint4){AL(u8v[h + 1], u8v[h]),     AL(u8v[h + 2], u8v[h + 1]),
                     AL(u8v[h + 3], u8v[h + 2]), AL(u8v[h + 4], u8v[h + 3])};
      *(uint4*)(bufl + c * CSTRIDE) = wv;
    }
  };

  // prologue: window 0 -> buf0; B depth D; A ring slots 0,1 (steps 0,1)
  stage(xw, sb0);
  #pragma unroll
  for (int d = 0; d < D; ++d)
    #pragma unroll
    for (int w = 0; w < W; ++w)
      breg[d][w] = *(const v8s*)(sp[w] + (d << 10));
  {
    const char* xrd0 = xw + xrd_off;
    #pragma unroll
    for (int j = 0; j < 2; ++j)
      #pragma unroll
      for (int m = 0; m < 2; ++m)
        areg[j][m] = *(const v8s*)(xrd0 + 64 * m + 32 * (UB - 1 - j));
  }

  #pragma unroll 1
  for (int g = 0; g < iters; ++g) {
    char* bufn = xw + (((g + 1) & 1) ? XBUF : 0);     // next window buffer
    const char* xrd  = xw + ((g & 1) ? XBUF : 0) + xrd_off;
    const char* xrdn = bufn + xrd_off;
    const int sbn = sb0 + UB * ((g + 1 < iters) ? g + 1 : g);  // clamp restage
    stage(bufn, sbn);
    #pragma unroll
    for (int ii = 0; ii < UB; ++ii) {
      // A prefetch for step ii+2 (crosses into next window at ii>=UB-2)
      {
        const char* pn = (ii + 2 < UB) ? xrd : xrdn;
        const int off = (ii + 2 < UB) ? 32 * (UB - 3 - ii) : 32 * (2 * UB - 3 - ii);
        #pragma unroll
        for (int m = 0; m < 2; ++m)
          areg[(ii + 2) & 3][m] = *(const v8s*)(pn + 64 * m + off);
      }
      // MFMA: one A fragment per m-stream x W live B tiles (B shared)
      #pragma unroll
      for (int w = 0; w < W; ++w)
        #pragma unroll
        for (int m = 0; m < 2; ++m)
          acc[m][4 - W + w] = __builtin_amdgcn_mfma_f32_32x32x16_bf16(
              areg[ii & 3][m], breg[ii % D][w], acc[m][4 - W + w], 0, 0, 0);
      // B refill: slot ii%D <- step ii+D (tail over-reads: rows < SWZSTEP, dead)
      #pragma unroll
      for (int w = 0; w < W; ++w)
        breg[ii % D][w] = *(const v8s*)(sp[w] + ((ii + D) << 10));
    }
    #pragma unroll
    for (int w = 0; w < W; ++w) sp[w] += (UB << 10);
  }
}

// ---- main kernel: 1024 blocks x 128 threads (2 waves k-split one 64t tile) ----
__global__ __launch_bounds__(128, 2) void blur_mfma(
    const float* __restrict__ xpad,
    const unsigned short* __restrict__ swz,
    const float* __restrict__ scale,
    float* __restrict__ out)
{
  __shared__ __align__(16) char xb[2 * 2 * XBUF];   // 33,280 B (2 waves x dbuf)
  const int tid  = threadIdx.x;
  const int lane = tid & 63;
  const int wid  = tid >> 6;
  const int b  = blockIdx.x;
  const int bc = b >> 6;                 // 16 bc x 64 t-chunks
  const int t0 = (b & 63) << 6;          // 64 output t per block (2 m-tiles)
  const int row = lane & 31, hi = lane >> 5;
  const float* __restrict__ xn = xpad + (size_t)bc * XPS + FRONT;
  const char* swzg = (const char*)swz;
  char* xw = xb + wid * (2 * XBUF);      // this wave's double-buffered region
  // A-read: copy c=row&7, byte 16*(row>>3) + 16*hi (+32/step, +64/m-stream)
  const int xrd_off = (row & 7) * CSTRIDE + 16 * (row >> 3) + 16 * hi;

  v16f acc[2][4];
  #pragma unroll
  for (int m = 0; m < 2; ++m)
    #pragma unroll
    for (int n = 0; n < 4; ++n)
      #pragma unroll
      for (int j = 0; j < 16; ++j) acc[m][n][j] = 0.0f;

  // regions (live: W4 s<20, W3 <49, W2 <124, W1 <313; extras hit zero B rows)
  // wave0: W4 0..23, W3 24..55, W2 56..103  (288 tile-steps)
  // wave1: W2 104..127, W1 128..319        (240 tile-steps)
  if (wid == 0) {
    run_roll<4, 24,  3>(swzg, xn, xw, xrd_off, t0, lane,   0, 1, acc);
    run_roll<3, 16,  4>(swzg, xn, xw, xrd_off, t0, lane,  24, 2, acc);
  }
  run_roll<2, 24,  6>(swzg, xn, xw, xrd_off, t0, lane,
                      wid ? 104 : 56, wid ? 1 : 2, acc);
  if (wid == 1)
    run_roll<1, 24, 12>(swzg, xn, xw, xrd_off, t0, lane, 128, 8, acc);

  // cross-wave reduction: 2 rounds of 16KB through the (dead) x region.
  __syncthreads();
  #pragma unroll
  for (int mm = 0; mm < 2; ++mm) {
    if (wid == 1) {
      #pragma unroll
      for (int n = 0; n < 4; ++n)
        #pragma unroll
        for (int r2 = 0; r2 < 4; ++r2) {
          v4f v = {acc[mm][n][4 * r2],     acc[mm][n][4 * r2 + 1],
                   acc[mm][n][4 * r2 + 2], acc[mm][n][4 * r2 + 3]};
          *(v4f*)(xb + ((n * 4 + r2) << 10) + 16 * lane) = v;
        }
    }
    __syncthreads();
    if (wid == 0) {
      #pragma unroll
      for (int n = 0; n < 4; ++n)
        #pragma unroll
        for (int r2 = 0; r2 < 4; ++r2) {
          v4f v = *(const v4f*)(xb + ((n * 4 + r2) << 10) + 16 * lane);
          acc[mm][n][4 * r2]     += v[0];
          acc[mm][n][4 * r2 + 1] += v[1];
          acc[mm][n][4 * r2 + 2] += v[2];
          acc[mm][n][4 * r2 + 3] += v[3];
        }
    }
    __syncthreads();                   // WAR guard before next round's writes
  }

  // epilogue (wave0): D col=lane&31 -> F, row=(reg&3)+8*(reg>>2)+4*hi -> t
  if (wid == 0) {
    #pragma unroll
    for (int m = 0; m < 2; ++m)
      #pragma unroll
      for (int n = 0; n < 4; ++n) {
        const int F = 32 * n + row;
        const float sc = scale[F];
        float* op = out + (size_t)(bc * NF + F) * T_OUT + t0 + 32 * m + 4 * hi;
        #pragma unroll
        for (int r2 = 0; r2 < 4; ++r2) {
          v4f o = {acc[m][n][4 * r2] * sc, acc[m][n][4 * r2 + 1] * sc,
                   acc[m][n][4 * r2 + 2] * sc, acc[m][n][4 * r2 + 3] * sc};
          *(v4f*)(op + 8 * r2) = o;
        }
      }
  }
}

extern "C" void kernel_launch(void* const* d_in, const int* in_sizes, int n_in,
                              void* d_out, int out_size, void* d_ws, size_t ws_size,
                              hipStream_t stream) {
  const float* noise = (const float*)d_in[0];   // (2, 8, 9095) fp32
  const float* filt  = (const float*)d_in[1];   // (128, 5000) fp32
  const float* scale = (const float*)d_in[2];   // (1, 128, 1) fp32
  float* out = (float*)d_out;                   // (2, 1024, 4096) fp32

  unsigned short* swz = (unsigned short*)d_ws;              // 1.44 MB
  float* xpad = (float*)((char*)d_ws + SWZ_BYTES);          // 16 x 9312 fp32

  const int pad_blocks = (NBC * XPS + 255) / 256;           // 582
  build_pre<<<352 + pad_blocks, 256, 0, stream>>>(filt, noise, swz, xpad);
  blur_mfma<<<1024, 128, 0, stream>>>(xpad, swz, scale, out);
}